// Round 1
// baseline (1371.774 us; speedup 1.0000x reference)
//
#include <hip/hip_runtime.h>
#include <math.h>

#define CC 256      // channels
#define NSP 4096    // H*W
#define BB 2        // batch
#define NHEADS 4
#define DH 64       // head dim (C/HEADS)

// ---------------------------------------------------------------------------
// conv1x1: dst[b,o,s] = bias[o] + sum_c W[o,c] * src[b,c,s] (* optional coef)
// coef (may be null): per-element scale coef[bh, i] with bh=b*4+c/64,
// i=(c%64)*64 + s/64  (the global-softmax row coefficient, applied on read).
// grid: (16 s-tiles, 16 o-tiles, B), block 256.
// ---------------------------------------------------------------------------
__global__ __launch_bounds__(256) void conv1x1_kernel(
    const float* __restrict__ src, const float* __restrict__ W,
    const float* __restrict__ bias, float* __restrict__ dst,
    const float* __restrict__ coef)
{
    __shared__ float xt[32][256];
    const int tid = threadIdx.x;
    const int s   = blockIdx.x * 256 + tid;
    const int o0  = blockIdx.y * 16;
    const int b   = blockIdx.z;

    float acc[16];
#pragma unroll
    for (int i = 0; i < 16; ++i) acc[i] = 0.f;

    for (int ct = 0; ct < 8; ++ct) {
        __syncthreads();
        for (int r = 0; r < 32; ++r) {
            const int c = ct * 32 + r;
            float v = src[((size_t)b * CC + c) * NSP + s];
            if (coef) {
                const int bh = b * NHEADS + (c >> 6);
                const int i  = ((c & 63) << 6) + (s >> 6);
                v *= coef[(size_t)bh * NSP + i];
            }
            xt[r][tid] = v;
        }
        __syncthreads();
        for (int cl = 0; cl < 32; ++cl) {
            const float xv = xt[cl][tid];
#pragma unroll
            for (int oo = 0; oo < 16; ++oo)
                acc[oo] += W[(o0 + oo) * CC + ct * 32 + cl] * xv;
        }
    }
#pragma unroll
    for (int oo = 0; oo < 16; ++oo)
        dst[((size_t)b * CC + o0 + oo) * NSP + s] = acc[oo] + bias[o0 + oo];
}

// ---------------------------------------------------------------------------
// Flash pass over kq = Kmat · Qmat^T with PER-ROW online max/sum.
// Row tile t of head hd == one contiguous channel slab of the conv tensor.
// Each block: 64 rows (one K slab). Thread (r=tid/4, sub=tid&3): K row in
// registers, processes i' = 4*q + sub over all 64 Q/V tiles.
// Outputs: Ou (unnormalized, conv layout), mrow, zrow per row.
// grid: (64 tiles, 8 bh), block 256.
// ---------------------------------------------------------------------------
__global__ __launch_bounds__(256) void flash_kernel(
    const float* __restrict__ Kc, const float* __restrict__ Qc,
    const float* __restrict__ Vc, float* __restrict__ Ou,
    float* __restrict__ mrow, float* __restrict__ zrow)
{
    __shared__ __align__(16) float Kt[64][68];   // pad 68: 16B-aligned rows, bank shift 4/row
    __shared__ __align__(16) float Qt[64][68];
    __shared__ __align__(16) float Vt[64][68];
    __shared__ float sm[4][64];
    __shared__ float sz[4][64];

    const int tid = threadIdx.x;
    const int t   = blockIdx.x;          // channel-within-head (== row tile)
    const int bh  = blockIdx.y;
    const int b   = bh >> 2;
    const int hd  = bh & 3;

    const size_t slab = ((size_t)(b * CC + hd * DH + t)) * NSP;

    for (int idx = tid; idx < 4096; idx += 256)
        Kt[idx >> 6][idx & 63] = Kc[slab + idx];
    __syncthreads();

    const int r   = tid >> 2;
    const int sub = tid & 3;

    float kreg[64];
    {
        const float4* kr = (const float4*)Kt[r];
#pragma unroll
        for (int k4 = 0; k4 < 16; ++k4) {
            const float4 kv = kr[k4];
            kreg[4*k4+0] = kv.x; kreg[4*k4+1] = kv.y;
            kreg[4*k4+2] = kv.z; kreg[4*k4+3] = kv.w;
        }
    }

    float Oa[64];
#pragma unroll
    for (int k = 0; k < 64; ++k) Oa[k] = 0.f;
    float m = -INFINITY, Z = 0.f;

    for (int tq = 0; tq < 64; ++tq) {
        __syncthreads();
        const size_t qslab = ((size_t)(b * CC + hd * DH + tq)) * NSP;
        for (int idx = tid; idx < 4096; idx += 256) {
            Qt[idx >> 6][idx & 63] = Qc[qslab + idx];
            Vt[idx >> 6][idx & 63] = Vc[qslab + idx];
        }
        __syncthreads();

        for (int q = 0; q < 16; ++q) {
            const int ii = (q << 2) | sub;   // 4 distinct rows/wave step, distinct banks
            float d = 0.f;
            {
                const float4* qr = (const float4*)Qt[ii];
#pragma unroll
                for (int k4 = 0; k4 < 16; ++k4) {
                    const float4 qv = qr[k4];
                    d += kreg[4*k4+0]*qv.x + kreg[4*k4+1]*qv.y
                       + kreg[4*k4+2]*qv.z + kreg[4*k4+3]*qv.w;
                }
            }
            const float4* vr = (const float4*)Vt[ii];
            if (d <= m) {                    // common path: no max update
                const float w = __expf(d - m);
                Z += w;
#pragma unroll
                for (int k4 = 0; k4 < 16; ++k4) {
                    const float4 vv = vr[k4];
                    Oa[4*k4+0] += w * vv.x; Oa[4*k4+1] += w * vv.y;
                    Oa[4*k4+2] += w * vv.z; Oa[4*k4+3] += w * vv.w;
                }
            } else {                         // rare: rescale accumulator
                const float sc = __expf(m - d);
                Z = Z * sc + 1.f;
#pragma unroll
                for (int k4 = 0; k4 < 16; ++k4) {
                    const float4 vv = vr[k4];
                    Oa[4*k4+0] = Oa[4*k4+0]*sc + vv.x;
                    Oa[4*k4+1] = Oa[4*k4+1]*sc + vv.y;
                    Oa[4*k4+2] = Oa[4*k4+2]*sc + vv.z;
                    Oa[4*k4+3] = Oa[4*k4+3]*sc + vv.w;
                }
                m = d;
            }
        }
    }

    // combine the 4 sub-partials per row
    sm[sub][r] = m;  sz[sub][r] = Z;
    __syncthreads();
    const float mr = fmaxf(fmaxf(sm[0][r], sm[1][r]), fmaxf(sm[2][r], sm[3][r]));
    const float myscale = __expf(m - mr);

    // zero Ocomb (reuse Kt), accumulate 4 partials with turn-taking
    for (int idx = tid; idx < 4096; idx += 256)
        Kt[idx >> 6][idx & 63] = 0.f;
    __syncthreads();
    for (int turn = 0; turn < 4; ++turn) {
        if (sub == turn) {
#pragma unroll
            for (int k = 0; k < 64; ++k) Kt[r][k] += myscale * Oa[k];
        }
        __syncthreads();
    }

    for (int idx = tid; idx < 4096; idx += 256)
        Ou[slab + idx] = Kt[idx >> 6][idx & 63];

    if (sub == 0) {
        const float zr = sz[0][r]*__expf(sm[0][r]-mr) + sz[1][r]*__expf(sm[1][r]-mr)
                       + sz[2][r]*__expf(sm[2][r]-mr) + sz[3][r]*__expf(sm[3][r]-mr);
        mrow[(size_t)bh * NSP + t * 64 + r] = mr;
        zrow[(size_t)bh * NSP + t * 64 + r] = zr;
    }
}

// ---------------------------------------------------------------------------
// Per-bh global softmax stats: m_g = max_i m_i ; Z_g = sum_i Z_i e^{m_i-m_g}
// coef[i] = e^{m_i - m_g} / Z_g.   grid: (8), block 256.
// ---------------------------------------------------------------------------
__global__ __launch_bounds__(256) void reduce_kernel(
    const float* __restrict__ mrow, const float* __restrict__ zrow,
    float* __restrict__ coef)
{
    __shared__ float red[256];
    const int tid = threadIdx.x;
    const int bh  = blockIdx.x;
    const float* mp = mrow + (size_t)bh * NSP;
    const float* zp = zrow + (size_t)bh * NSP;

    float lm = -INFINITY;
    for (int i = tid; i < NSP; i += 256) lm = fmaxf(lm, mp[i]);
    red[tid] = lm; __syncthreads();
    for (int s = 128; s > 0; s >>= 1) {
        if (tid < s) red[tid] = fmaxf(red[tid], red[tid + s]);
        __syncthreads();
    }
    const float mg = red[0];
    __syncthreads();

    float lz = 0.f;
    for (int i = tid; i < NSP; i += 256) lz += zp[i] * __expf(mp[i] - mg);
    red[tid] = lz; __syncthreads();
    for (int s = 128; s > 0; s >>= 1) {
        if (tid < s) red[tid] += red[tid + s];
        __syncthreads();
    }
    const float Zg  = red[0];
    const float inv = 1.f / Zg;
    for (int i = tid; i < NSP; i += 256)
        coef[(size_t)bh * NSP + i] = __expf(mp[i] - mg) * inv;
}

// ---------------------------------------------------------------------------
extern "C" void kernel_launch(void* const* d_in, const int* in_sizes, int n_in,
                              void* d_out, int out_size, void* d_ws, size_t ws_size,
                              hipStream_t stream)
{
    (void)in_sizes; (void)n_in; (void)out_size; (void)ws_size;
    const float* in1 = (const float*)d_in[0];
    const float* in2 = (const float*)d_in[1];
    const float* W1  = (const float*)d_in[2]; const float* b1 = (const float*)d_in[3];
    const float* W2  = (const float*)d_in[4]; const float* b2 = (const float*)d_in[5];
    const float* W3  = (const float*)d_in[6]; const float* b3 = (const float*)d_in[7];
    const float* W4  = (const float*)d_in[8]; const float* b4 = (const float*)d_in[9];
    float* out = (float*)d_out;
    float* ws  = (float*)d_ws;

    const size_t TEN = (size_t)BB * CC * NSP;   // 2,097,152
    float* Kc   = ws;
    float* Qc   = Kc + TEN;
    float* Vc   = Qc + TEN;
    float* Ou   = Vc + TEN;
    float* mrow = Ou + TEN;                     // 8*4096
    float* zrow = mrow + (size_t)BB * NHEADS * NSP;
    float* coef = zrow + (size_t)BB * NHEADS * NSP;

    dim3 cgrid(16, 16, BB);
    conv1x1_kernel<<<cgrid, 256, 0, stream>>>(in1, W1, b1, Kc, nullptr);
    conv1x1_kernel<<<cgrid, 256, 0, stream>>>(in1, W2, b2, Qc, nullptr);
    conv1x1_kernel<<<cgrid, 256, 0, stream>>>(in2, W3, b3, Vc, nullptr);
    flash_kernel<<<dim3(64, BB * NHEADS), 256, 0, stream>>>(Kc, Qc, Vc, Ou, mrow, zrow);
    reduce_kernel<<<dim3(BB * NHEADS), 256, 0, stream>>>(mrow, zrow, coef);
    conv1x1_kernel<<<cgrid, 256, 0, stream>>>(Ou, W4, b4, out, coef);
}

// Round 2
// 561.871 us; speedup vs baseline: 2.4414x; 2.4414x over previous
//
#include <hip/hip_runtime.h>
#include <math.h>

#define CC 256      // channels
#define NSP 4096    // H*W
#define BB 2        // batch
#define NHEADS 4
#define CSHIFT 48.0f

typedef float f32x4 __attribute__((ext_vector_type(4)));
typedef short short8 __attribute__((ext_vector_type(8)));

// round-to-nearest-even f32 -> bf16 bits (finite inputs)
__device__ __forceinline__ unsigned short bf16rne(float x) {
    unsigned u = __float_as_uint(x);
    u += 0x7FFFu + ((u >> 16) & 1u);
    return (unsigned short)(u >> 16);
}

// ---------------------------------------------------------------------------
// conv1x1: dst[b,o,s] = bias[o] + sum_c W[o,c] * src[b,c,s] (* optional coef)
// coef (may be null): per-BH scalar 1/Z_g, bh = b*4 + c/64.
// grid: (16 s-tiles, 16 o-tiles, B), block 256.   [unchanged from R0 baseline]
// ---------------------------------------------------------------------------
__global__ __launch_bounds__(256) void conv1x1_kernel(
    const float* __restrict__ src, const float* __restrict__ W,
    const float* __restrict__ bias, float* __restrict__ dst,
    const float* __restrict__ coef)
{
    __shared__ float xt[32][256];
    const int tid = threadIdx.x;
    const int s   = blockIdx.x * 256 + tid;
    const int o0  = blockIdx.y * 16;
    const int b   = blockIdx.z;

    float acc[16];
#pragma unroll
    for (int i = 0; i < 16; ++i) acc[i] = 0.f;

    for (int ct = 0; ct < 8; ++ct) {
        __syncthreads();
        for (int r = 0; r < 32; ++r) {
            const int c = ct * 32 + r;
            float v = src[((size_t)b * CC + c) * NSP + s];
            if (coef) v *= coef[b * NHEADS + (c >> 6)];
            xt[r][tid] = v;
        }
        __syncthreads();
        for (int cl = 0; cl < 32; ++cl) {
            const float xv = xt[cl][tid];
#pragma unroll
            for (int oo = 0; oo < 16; ++oo)
                acc[oo] += W[(o0 + oo) * CC + ct * 32 + cl] * xv;
        }
    }
#pragma unroll
    for (int oo = 0; oo < 16; ++oo)
        dst[((size_t)b * CC + o0 + oo) * NSP + s] = acc[oo] + bias[o0 + oo];
}

// ---------------------------------------------------------------------------
// LDS staging helpers. All tiles are 64x64 bf16, row-major, row stride 128 B,
// XOR-swizzled: byte_off ^= (row&7)<<4  (G4 fix for stride-128B ds_read_b128).
// ---------------------------------------------------------------------------
__device__ __forceinline__ void stage_hilo(const float* __restrict__ src,
                                           unsigned short* hi, unsigned short* lo,
                                           int tid)
{
#pragma unroll
    for (int i = 0; i < 4; ++i) {
        const int f4 = tid + 256 * i;         // float4 index 0..1023
        const int h  = f4 >> 4;               // row 0..63
        const int k4 = f4 & 15;               // float4 within row
        const float4 v = ((const float4*)src)[f4];
        ushort4 vh, vl;
        {
            unsigned short b0 = bf16rne(v.x);
            vh.x = b0; vl.x = bf16rne(v.x - __uint_as_float((unsigned)b0 << 16));
        }
        {
            unsigned short b0 = bf16rne(v.y);
            vh.y = b0; vl.y = bf16rne(v.y - __uint_as_float((unsigned)b0 << 16));
        }
        {
            unsigned short b0 = bf16rne(v.z);
            vh.z = b0; vl.z = bf16rne(v.z - __uint_as_float((unsigned)b0 << 16));
        }
        {
            unsigned short b0 = bf16rne(v.w);
            vh.w = b0; vl.w = bf16rne(v.w - __uint_as_float((unsigned)b0 << 16));
        }
        const int off = (h * 128 + k4 * 8) ^ ((h & 7) << 4);
        *(ushort4*)((char*)hi + off) = vh;
        *(ushort4*)((char*)lo + off) = vl;
    }
}

// V arrives as [j][f] (row-major); store transposed Vt[f][j] (bf16, swizzled).
// Gather: each thread produces 4 consecutive-j bf16 for one f -> one b64 write.
// Global reads stay coalesced (lane index == f).
__device__ __forceinline__ void stage_vt(const float* __restrict__ src,
                                         unsigned short* vt, int tid)
{
#pragma unroll
    for (int i = 0; i < 4; ++i) {
        const int qid = tid + 256 * i;        // 0..1023
        const int f   = qid & 63;
        const int j0  = (qid >> 6) * 4;       // 0,4,...,60
        const float a0 = src[(j0 + 0) * 64 + f];
        const float a1 = src[(j0 + 1) * 64 + f];
        const float a2 = src[(j0 + 2) * 64 + f];
        const float a3 = src[(j0 + 3) * 64 + f];
        ushort4 w4;
        w4.x = bf16rne(a0); w4.y = bf16rne(a1);
        w4.z = bf16rne(a2); w4.w = bf16rne(a3);
        const int off = (f * 128 + j0 * 2) ^ ((f & 7) << 4);
        *(ushort4*)((char*)vt + off) = w4;
    }
}

// MFMA fragment read: 8 contiguous bf16 at (row, k0) from swizzled 64-wide tile
__device__ __forceinline__ short8 read_frag8(const unsigned short* base,
                                             int row, int k0)
{
    const int off = (row * 128 + k0 * 2) ^ ((row & 7) << 4);
    return *(const short8*)((const char*)base + off);
}

// ---------------------------------------------------------------------------
// MFMA flash kernel, global-shift softmax (no per-row max needed):
//   S = K·Q^T via bf16 hi/lo split (3 products), P = exp(S - 48) in bf16,
//   O += P·V, Z_row += sum(P).  Normalization = single 1/Z_g per bh, applied
//   in the final conv.
// Block: 256 thr (4 waves), 64 rows (1 K slab); wave w owns rows w*16..w*16+15.
// grid: 512 linear; bh = id&7 (== XCD for L2 locality), t = id>>3.
// ---------------------------------------------------------------------------
__global__ __launch_bounds__(256) void flash_mfma(
    const float* __restrict__ Kc, const float* __restrict__ Qc,
    const float* __restrict__ Vc, float* __restrict__ Ou,
    float* __restrict__ zrow)
{
    __shared__ __align__(16) unsigned short Qhi[64 * 64];   // 8 KB
    __shared__ __align__(16) unsigned short Qlo[64 * 64];   // 8 KB
    __shared__ __align__(16) unsigned short Vt [64 * 64];   // 8 KB
    __shared__ __align__(16) unsigned short Pb [4][16 * 64];// 8 KB (per wave)

    const int tid = threadIdx.x;
    const int w   = tid >> 6;        // wave id
    const int l   = tid & 63;        // lane
    const int lr  = l & 15;          // 16-lane group index
    const int g   = l >> 4;          // quarter-wave id

    const int id = blockIdx.x;
    const int bh = id & 7;           // -> XCD (one bh per XCD: 3 MB fits L2)
    const int t  = id >> 3;          // K row-tile
    const int b  = bh >> 2;
    const int hd = bh & 3;

    const size_t slabK = ((size_t)(b * CC + hd * 64 + t)) * NSP;

    // ---- stage K slab (reuse Qhi/Qlo space), pull K frags into registers ----
    stage_hilo(Kc + slabK, Qhi, Qlo, tid);
    __syncthreads();
    short8 khi[2], klo[2];
    {
        const int row = w * 16 + lr;
#pragma unroll
        for (int ks = 0; ks < 2; ++ks) {
            khi[ks] = read_frag8(Qhi, row, g * 8 + ks * 32);
            klo[ks] = read_frag8(Qlo, row, g * 8 + ks * 32);
        }
    }
    __syncthreads();

    f32x4 oacc[4];
    float zacc[4];
#pragma unroll
    for (int nf = 0; nf < 4; ++nf) {
        oacc[nf] = (f32x4){0.f, 0.f, 0.f, 0.f};
        zacc[nf] = 0.f;
    }

    unsigned short* Pw = Pb[w];

    for (int tq = 0; tq < 64; ++tq) {
        const size_t slabQ = ((size_t)(b * CC + hd * 64 + tq)) * NSP;
        stage_hilo(Qc + slabQ, Qhi, Qlo, tid);
        stage_vt (Vc + slabQ, Vt, tid);
        __syncthreads();

        // ---- S = K·Q^T  (hi*hi + hi*lo + lo*hi) ----
        f32x4 s[4];
#pragma unroll
        for (int nf = 0; nf < 4; ++nf) {
            f32x4 acc = {0.f, 0.f, 0.f, 0.f};
#pragma unroll
            for (int ks = 0; ks < 2; ++ks) {
                const int qrow   = nf * 16 + lr;
                const int kchunk = g * 8 + ks * 32;
                const short8 qh = read_frag8(Qhi, qrow, kchunk);
                const short8 ql = read_frag8(Qlo, qrow, kchunk);
                acc = __builtin_amdgcn_mfma_f32_16x16x32_bf16(khi[ks], qh, acc, 0, 0, 0);
                acc = __builtin_amdgcn_mfma_f32_16x16x32_bf16(khi[ks], ql, acc, 0, 0, 0);
                acc = __builtin_amdgcn_mfma_f32_16x16x32_bf16(klo[ks], qh, acc, 0, 0, 0);
            }
            s[nf] = acc;
        }

        // ---- P = exp(S - 48) -> bf16 LDS; Z accumulate per lane ----
#pragma unroll
        for (int nf = 0; nf < 4; ++nf) {
#pragma unroll
            for (int reg = 0; reg < 4; ++reg) {
                const float p = __expf(s[nf][reg] - CSHIFT);
                zacc[reg] += p;
                const int row = g * 4 + reg;           // D-layout row
                const int col = nf * 16 + lr;          // D-layout col
                const int off = (row * 128 + col * 2) ^ ((row & 7) << 4);
                *(unsigned short*)((char*)Pw + off) = bf16rne(p);
            }
        }

        // ---- O += P·V ----
#pragma unroll
        for (int ks = 0; ks < 2; ++ks) {
            const short8 pa = read_frag8(Pw, lr, g * 8 + ks * 32);
#pragma unroll
            for (int nf = 0; nf < 4; ++nf) {
                const short8 vb = read_frag8(Vt, nf * 16 + lr, g * 8 + ks * 32);
                oacc[nf] = __builtin_amdgcn_mfma_f32_16x16x32_bf16(pa, vb, oacc[nf], 0, 0, 0);
            }
        }
        __syncthreads();
    }

    // ---- per-row Z: reduce across the 16 lanes of each quarter-wave ----
#pragma unroll
    for (int reg = 0; reg < 4; ++reg) {
        float z = zacc[reg];
        z += __shfl_xor(z, 1);
        z += __shfl_xor(z, 2);
        z += __shfl_xor(z, 4);
        z += __shfl_xor(z, 8);
        if (lr == 0)
            zrow[(size_t)bh * NSP + t * 64 + w * 16 + g * 4 + reg] = z;
    }

    // ---- write unnormalized O (conv layout == slab layout) ----
#pragma unroll
    for (int nf = 0; nf < 4; ++nf)
#pragma unroll
        for (int reg = 0; reg < 4; ++reg)
            Ou[slabK + (size_t)(w * 16 + g * 4 + reg) * 64 + nf * 16 + lr] = oacc[nf][reg];
}

// ---------------------------------------------------------------------------
// Per-bh: Z_g = sum_i Z_i ; coef[bh] = 1/Z_g.   grid: (8), block 256.
// ---------------------------------------------------------------------------
__global__ __launch_bounds__(256) void reduce_kernel(
    const float* __restrict__ zrow, float* __restrict__ coef)
{
    __shared__ float red[256];
    const int tid = threadIdx.x;
    const int bh  = blockIdx.x;
    const float* zp = zrow + (size_t)bh * NSP;

    float lz = 0.f;
    for (int i = tid; i < NSP; i += 256) lz += zp[i];
    red[tid] = lz; __syncthreads();
    for (int s = 128; s > 0; s >>= 1) {
        if (tid < s) red[tid] += red[tid + s];
        __syncthreads();
    }
    if (tid == 0) coef[bh] = 1.f / red[0];
}

// ---------------------------------------------------------------------------
extern "C" void kernel_launch(void* const* d_in, const int* in_sizes, int n_in,
                              void* d_out, int out_size, void* d_ws, size_t ws_size,
                              hipStream_t stream)
{
    (void)in_sizes; (void)n_in; (void)out_size; (void)ws_size;
    const float* in1 = (const float*)d_in[0];
    const float* in2 = (const float*)d_in[1];
    const float* W1  = (const float*)d_in[2]; const float* b1 = (const float*)d_in[3];
    const float* W2  = (const float*)d_in[4]; const float* b2 = (const float*)d_in[5];
    const float* W3  = (const float*)d_in[6]; const float* b3 = (const float*)d_in[7];
    const float* W4  = (const float*)d_in[8]; const float* b4 = (const float*)d_in[9];
    float* out = (float*)d_out;
    float* ws  = (float*)d_ws;

    const size_t TEN = (size_t)BB * CC * NSP;   // 2,097,152 floats
    float* Kc   = ws;
    float* Qc   = Kc + TEN;
    float* Vc   = Qc + TEN;
    float* Ou   = Vc + TEN;
    float* zrow = Ou + TEN;                     // 8*4096
    float* coef = zrow + (size_t)BB * NHEADS * NSP;

    dim3 cgrid(16, 16, BB);
    conv1x1_kernel<<<cgrid, 256, 0, stream>>>(in1, W1, b1, Kc, nullptr);
    conv1x1_kernel<<<cgrid, 256, 0, stream>>>(in1, W2, b2, Qc, nullptr);
    conv1x1_kernel<<<cgrid, 256, 0, stream>>>(in2, W3, b3, Vc, nullptr);
    flash_mfma<<<dim3(512), 256, 0, stream>>>(Kc, Qc, Vc, Ou, zrow);
    reduce_kernel<<<dim3(BB * NHEADS), 256, 0, stream>>>(zrow, coef);
    conv1x1_kernel<<<cgrid, 256, 0, stream>>>(Ou, W4, b4, out, coef);
}

// Round 3
// 497.766 us; speedup vs baseline: 2.7559x; 1.1288x over previous
//
#include <hip/hip_runtime.h>
#include <math.h>

#define CC 256      // channels
#define NSP 4096    // H*W
#define BB 2        // batch
#define NHEADS 4
#define CSHIFT 48.0f

typedef float f32x4 __attribute__((ext_vector_type(4)));
typedef short short8 __attribute__((ext_vector_type(8)));
typedef unsigned short u16;

// round-to-nearest-even f32 -> bf16 bits (finite inputs)
__device__ __forceinline__ u16 bf16rne(float x) {
    unsigned u = __float_as_uint(x);
    u += 0x7FFFu + ((u >> 16) & 1u);
    return (u16)(u >> 16);
}

// ---------------------------------------------------------------------------
// conv1x1 (unchanged, known-good): dst[b,o,s] = bias[o] + sum_c W[o,c]*src[b,c,s]
// coef (may be null): per-BH scalar 1/Z_g, bh = b*4 + c/64.
// grid: (16 s-tiles, 16 o-tiles, B), block 256.
// ---------------------------------------------------------------------------
__global__ __launch_bounds__(256) void conv1x1_kernel(
    const float* __restrict__ src, const float* __restrict__ W,
    const float* __restrict__ bias, float* __restrict__ dst,
    const float* __restrict__ coef)
{
    __shared__ float xt[32][256];
    const int tid = threadIdx.x;
    const int s   = blockIdx.x * 256 + tid;
    const int o0  = blockIdx.y * 16;
    const int b   = blockIdx.z;

    float acc[16];
#pragma unroll
    for (int i = 0; i < 16; ++i) acc[i] = 0.f;

    for (int ct = 0; ct < 8; ++ct) {
        __syncthreads();
        for (int r = 0; r < 32; ++r) {
            const int c = ct * 32 + r;
            float v = src[((size_t)b * CC + c) * NSP + s];
            if (coef) v *= coef[b * NHEADS + (c >> 6)];
            xt[r][tid] = v;
        }
        __syncthreads();
        for (int cl = 0; cl < 32; ++cl) {
            const float xv = xt[cl][tid];
#pragma unroll
            for (int oo = 0; oo < 16; ++oo)
                acc[oo] += W[(o0 + oo) * CC + ct * 32 + cl] * xv;
        }
    }
#pragma unroll
    for (int oo = 0; oo < 16; ++oo)
        dst[((size_t)b * CC + o0 + oo) * NSP + s] = acc[oo] + bias[o0 + oo];
}

// ---------------------------------------------------------------------------
// pack_kernel: per (bh,t) slab, produce MFMA-ready pre-swizzled bf16 tiles:
//   Khi/Klo, Qhi/Qlo: element (r,f) at byte (r*128 + f*2) ^ ((r&7)<<4)
//   Vt (transposed):  element (f,j) at byte (f*128 + j*2) ^ ((f&7)<<4)
// The XOR pre-swizzle in GLOBAL lets flash2 stage with linear global_load_lds
// and read fragments conflict-free (rule 21: both-sides involution).
// grid: 512 = bh*64 + t, block 256.
// ---------------------------------------------------------------------------
__global__ __launch_bounds__(256) void pack_kernel(
    const float* __restrict__ Kc, const float* __restrict__ Qc,
    const float* __restrict__ Vc,
    u16* __restrict__ Khi, u16* __restrict__ Klo,
    u16* __restrict__ Qhi, u16* __restrict__ Qlo,
    u16* __restrict__ Vtg)
{
    __shared__ __align__(16) u16 vt_lds[64][72];   // stride 144B: 16B-aligned rows

    const int tid = threadIdx.x;
    const int id  = blockIdx.x;
    const int bh  = id >> 6, t = id & 63;
    const int b   = bh >> 2, hd = bh & 3;
    const size_t slab = ((size_t)(b * CC + hd * 64 + t)) * NSP;

    const float4* Ks = (const float4*)(Kc + slab);
    const float4* Qs = (const float4*)(Qc + slab);
    const float4* Vs = (const float4*)(Vc + slab);

    char* KhiT = (char*)(Khi + (size_t)id * 4096);
    char* KloT = (char*)(Klo + (size_t)id * 4096);
    char* QhiT = (char*)(Qhi + (size_t)id * 4096);
    char* QloT = (char*)(Qlo + (size_t)id * 4096);
    char* VtT  = (char*)(Vtg + (size_t)id * 4096);

#pragma unroll
    for (int i = 0; i < 4; ++i) {
        const int f4 = tid + 256 * i;        // float4 index 0..1023
        const int r  = f4 >> 4, fq = f4 & 15;
        const int off = (r * 128 + fq * 8) ^ ((r & 7) << 4);

        float4 kv = Ks[f4];
        ushort4 h4, l4;
        h4.x = bf16rne(kv.x); l4.x = bf16rne(kv.x - __uint_as_float((unsigned)h4.x << 16));
        h4.y = bf16rne(kv.y); l4.y = bf16rne(kv.y - __uint_as_float((unsigned)h4.y << 16));
        h4.z = bf16rne(kv.z); l4.z = bf16rne(kv.z - __uint_as_float((unsigned)h4.z << 16));
        h4.w = bf16rne(kv.w); l4.w = bf16rne(kv.w - __uint_as_float((unsigned)h4.w << 16));
        *(ushort4*)(KhiT + off) = h4;
        *(ushort4*)(KloT + off) = l4;

        float4 qv = Qs[f4];
        h4.x = bf16rne(qv.x); l4.x = bf16rne(qv.x - __uint_as_float((unsigned)h4.x << 16));
        h4.y = bf16rne(qv.y); l4.y = bf16rne(qv.y - __uint_as_float((unsigned)h4.y << 16));
        h4.z = bf16rne(qv.z); l4.z = bf16rne(qv.z - __uint_as_float((unsigned)h4.z << 16));
        h4.w = bf16rne(qv.w); l4.w = bf16rne(qv.w - __uint_as_float((unsigned)h4.w << 16));
        *(ushort4*)(QhiT + off) = h4;
        *(ushort4*)(QloT + off) = l4;

        float4 vv = Vs[f4];                  // elements (j=r, f=fq*4+e)
        vt_lds[fq * 4 + 0][r] = bf16rne(vv.x);
        vt_lds[fq * 4 + 1][r] = bf16rne(vv.y);
        vt_lds[fq * 4 + 2][r] = bf16rne(vv.z);
        vt_lds[fq * 4 + 3][r] = bf16rne(vv.w);
    }
    __syncthreads();
#pragma unroll
    for (int i = 0; i < 2; ++i) {
        const int chunk = tid + 256 * i;     // 0..511
        const int f = chunk >> 3, j8 = chunk & 7;
        const uint4 vv = *(const uint4*)&vt_lds[f][j8 * 8];
        const int off = (f * 128 + j8 * 16) ^ ((f & 7) << 4);
        *(uint4*)(VtT + off) = vv;
    }
}

// ---------------------------------------------------------------------------
// flash2: S = K·Q^T (bf16 hi/lo, 3 products), P = exp(S-48) bf16, O += P·V,
// Z_row accumulated per lane. 128 threads = 2 waves; each wave owns 32 K-rows
// (2 A-frag sets -> every Q/V fragment read feeds 2 MFMAs). Double-buffered
// global_load_lds staging of pre-swizzled tiles (zero staging VALU).
// grid: 512; bh = id&7 (XCD-pinned), t = id>>3.
// ---------------------------------------------------------------------------
__device__ __forceinline__ void glds16(const void* gsrc, void* ldst) {
    __builtin_amdgcn_global_load_lds(
        (const __attribute__((address_space(1))) void*)gsrc,
        (__attribute__((address_space(3))) void*)ldst, 16, 0, 0);
}

__device__ __forceinline__ short8 frag8(const u16* base, int row, int k0) {
    const int off = (row * 128 + k0 * 2) ^ ((row & 7) << 4);
    return *(const short8*)((const char*)base + off);
}

__global__ __launch_bounds__(128) void flash2(
    const u16* __restrict__ Khi, const u16* __restrict__ Klo,
    const u16* __restrict__ Qhi, const u16* __restrict__ Qlo,
    const u16* __restrict__ Vtg,
    float* __restrict__ Ou, float* __restrict__ zrow)
{
    __shared__ __align__(16) u16 Qh[2][4096];    // 16 KB
    __shared__ __align__(16) u16 Ql[2][4096];    // 16 KB
    __shared__ __align__(16) u16 Vt[2][4096];    // 16 KB
    __shared__ __align__(16) u16 Pw[2][2048];    // 8 KB (32x64 per wave)

    const int tid = threadIdx.x;
    const int w  = tid >> 6, l = tid & 63;
    const int lr = l & 15,  g = l >> 4;
    const int id = blockIdx.x;
    const int bh = id & 7, t = id >> 3;
    const int b  = bh >> 2, hd = bh & 3;
    const size_t slab = ((size_t)(b * CC + hd * 64 + t)) * NSP;

    // ---- K fragments straight from pre-swizzled global ----
    const char* KhiT = (const char*)(Khi + (size_t)(bh * 64 + t) * 4096);
    const char* KloT = (const char*)(Klo + (size_t)(bh * 64 + t) * 4096);
    short8 khi[2][2], klo[2][2];
#pragma unroll
    for (int set = 0; set < 2; ++set) {
        const int row = w * 32 + set * 16 + lr;
#pragma unroll
        for (int ks = 0; ks < 2; ++ks) {
            const int off = (row * 128 + (g * 8 + ks * 32) * 2) ^ ((row & 7) << 4);
            khi[set][ks] = *(const short8*)(KhiT + off);
            klo[set][ks] = *(const short8*)(KloT + off);
        }
    }

    const char* QhiB = (const char*)(Qhi + (size_t)bh * 64 * 4096);
    const char* QloB = (const char*)(Qlo + (size_t)bh * 64 * 4096);
    const char* VtB  = (const char*)(Vtg + (size_t)bh * 64 * 4096);

    auto stage = [&](int buf, int tq) {
        const char* gq = QhiB + (size_t)tq * 8192;
        const char* gl = QloB + (size_t)tq * 8192;
        const char* gv = VtB  + (size_t)tq * 8192;
#pragma unroll
        for (int c = 0; c < 4; ++c) {
            const int o = (w * 4 + c) * 1024;
            glds16(gq + o + l * 16, (char*)Qh[buf] + o);
            glds16(gl + o + l * 16, (char*)Ql[buf] + o);
            glds16(gv + o + l * 16, (char*)Vt[buf] + o);
        }
    };

    f32x4 oacc[2][4];
    float zacc[2][4];
#pragma unroll
    for (int set = 0; set < 2; ++set)
#pragma unroll
        for (int nf = 0; nf < 4; ++nf) {
            oacc[set][nf] = (f32x4){0.f, 0.f, 0.f, 0.f};
            zacc[set][nf] = 0.f;
        }

    u16* Pme = Pw[w];

    stage(0, 0);
    asm volatile("s_waitcnt vmcnt(0)" ::: "memory");
    __syncthreads();

    for (int tq = 0; tq < 64; ++tq) {
        const int cur = tq & 1;
        if (tq < 63) stage(cur ^ 1, tq + 1);   // async prefetch (T3 minimal)

        const u16* qh_t = Qh[cur];
        const u16* ql_t = Ql[cur];
        const u16* vt_t = Vt[cur];

        // ---- S = K·Q^T (hi*hi + lo*hi + hi*lo), P = exp(S-48) -> Pw ----
#pragma unroll
        for (int nf = 0; nf < 4; ++nf) {
            f32x4 a0 = {0.f, 0.f, 0.f, 0.f}, a1 = {0.f, 0.f, 0.f, 0.f};
#pragma unroll
            for (int ks = 0; ks < 2; ++ks) {
                const short8 qh = frag8(qh_t, nf * 16 + lr, g * 8 + ks * 32);
                const short8 ql = frag8(ql_t, nf * 16 + lr, g * 8 + ks * 32);
                a0 = __builtin_amdgcn_mfma_f32_16x16x32_bf16(khi[0][ks], qh, a0, 0, 0, 0);
                a1 = __builtin_amdgcn_mfma_f32_16x16x32_bf16(khi[1][ks], qh, a1, 0, 0, 0);
                a0 = __builtin_amdgcn_mfma_f32_16x16x32_bf16(klo[0][ks], qh, a0, 0, 0, 0);
                a1 = __builtin_amdgcn_mfma_f32_16x16x32_bf16(klo[1][ks], qh, a1, 0, 0, 0);
                a0 = __builtin_amdgcn_mfma_f32_16x16x32_bf16(khi[0][ks], ql, a0, 0, 0, 0);
                a1 = __builtin_amdgcn_mfma_f32_16x16x32_bf16(khi[1][ks], ql, a1, 0, 0, 0);
            }
#pragma unroll
            for (int reg = 0; reg < 4; ++reg) {
                const float p0 = __expf(a0[reg] - CSHIFT);
                const float p1 = __expf(a1[reg] - CSHIFT);
                zacc[0][reg] += p0;
                zacc[1][reg] += p1;
                const int r0 = g * 4 + reg, r1 = 16 + g * 4 + reg;
                const int c2 = (nf * 16 + lr) * 2;
                *(u16*)((char*)Pme + ((r0 * 128 + c2) ^ ((r0 & 7) << 4))) = bf16rne(p0);
                *(u16*)((char*)Pme + ((r1 * 128 + c2) ^ ((r1 & 7) << 4))) = bf16rne(p1);
            }
        }

        // ---- O += P·V ----
        short8 pa[2][2];
#pragma unroll
        for (int set = 0; set < 2; ++set)
#pragma unroll
            for (int ks = 0; ks < 2; ++ks)
                pa[set][ks] = frag8(Pme, set * 16 + lr, g * 8 + ks * 32);
#pragma unroll
        for (int ks = 0; ks < 2; ++ks)
#pragma unroll
            for (int nf = 0; nf < 4; ++nf) {
                const short8 vb = frag8(vt_t, nf * 16 + lr, g * 8 + ks * 32);
                oacc[0][nf] = __builtin_amdgcn_mfma_f32_16x16x32_bf16(pa[0][ks], vb, oacc[0][nf], 0, 0, 0);
                oacc[1][nf] = __builtin_amdgcn_mfma_f32_16x16x32_bf16(pa[1][ks], vb, oacc[1][nf], 0, 0, 0);
            }

        asm volatile("s_waitcnt vmcnt(0)" ::: "memory");
        __syncthreads();
    }

    // ---- per-row Z (reduce 16 lanes of each quarter-wave group) ----
#pragma unroll
    for (int set = 0; set < 2; ++set)
#pragma unroll
        for (int reg = 0; reg < 4; ++reg) {
            float z = zacc[set][reg];
            z += __shfl_xor(z, 1);
            z += __shfl_xor(z, 2);
            z += __shfl_xor(z, 4);
            z += __shfl_xor(z, 8);
            if (lr == 0)
                zrow[(size_t)bh * NSP + t * 64 + w * 32 + set * 16 + g * 4 + reg] = z;
        }

    // ---- write unnormalized O (slab layout) ----
#pragma unroll
    for (int set = 0; set < 2; ++set)
#pragma unroll
        for (int nf = 0; nf < 4; ++nf)
#pragma unroll
            for (int reg = 0; reg < 4; ++reg)
                Ou[slab + (size_t)(w * 32 + set * 16 + g * 4 + reg) * 64 + nf * 16 + lr]
                    = oacc[set][nf][reg];
}

// ---------------------------------------------------------------------------
// Per-bh: Z_g = sum_i Z_i ; coef[bh] = 1/Z_g.   grid: (8), block 256.
// ---------------------------------------------------------------------------
__global__ __launch_bounds__(256) void reduce_kernel(
    const float* __restrict__ zrow, float* __restrict__ coef)
{
    __shared__ float red[256];
    const int tid = threadIdx.x;
    const int bh  = blockIdx.x;
    const float* zp = zrow + (size_t)bh * NSP;

    float lz = 0.f;
    for (int i = tid; i < NSP; i += 256) lz += zp[i];
    red[tid] = lz; __syncthreads();
    for (int s = 128; s > 0; s >>= 1) {
        if (tid < s) red[tid] += red[tid + s];
        __syncthreads();
    }
    if (tid == 0) coef[bh] = 1.f / red[0];
}

// ---------------------------------------------------------------------------
extern "C" void kernel_launch(void* const* d_in, const int* in_sizes, int n_in,
                              void* d_out, int out_size, void* d_ws, size_t ws_size,
                              hipStream_t stream)
{
    (void)in_sizes; (void)n_in; (void)out_size; (void)ws_size;
    const float* in1 = (const float*)d_in[0];
    const float* in2 = (const float*)d_in[1];
    const float* W1  = (const float*)d_in[2]; const float* b1 = (const float*)d_in[3];
    const float* W2  = (const float*)d_in[4]; const float* b2 = (const float*)d_in[5];
    const float* W3  = (const float*)d_in[6]; const float* b3 = (const float*)d_in[7];
    const float* W4  = (const float*)d_in[8]; const float* b4 = (const float*)d_in[9];
    float* out = (float*)d_out;
    float* ws  = (float*)d_ws;

    const size_t TEN = (size_t)BB * CC * NSP;   // 2,097,152 elements
    float* Kc = ws;                              // 8 MB (reused as Ou after pack)
    float* Qc = Kc + TEN;                        // 8 MB
    float* Vc = Qc + TEN;                        // 8 MB
    float* Ou = Kc;                              // alias: Kc dead after pack
    u16* Khi  = (u16*)(ws + 3 * TEN);            // 5 x 4 MB packed tiles
    u16* Klo  = Khi + TEN;
    u16* Qhi  = Klo + TEN;
    u16* Qlo  = Qhi + TEN;
    u16* Vtg  = Qlo + TEN;
    float* zrow = (float*)(Vtg + TEN);           // 8*4096 f32
    float* coef = zrow + (size_t)BB * NHEADS * NSP;

    dim3 cgrid(16, 16, BB);
    conv1x1_kernel<<<cgrid, 256, 0, stream>>>(in1, W1, b1, Kc, nullptr);
    conv1x1_kernel<<<cgrid, 256, 0, stream>>>(in1, W2, b2, Qc, nullptr);
    conv1x1_kernel<<<cgrid, 256, 0, stream>>>(in2, W3, b3, Vc, nullptr);
    pack_kernel<<<dim3(512), 256, 0, stream>>>(Kc, Qc, Vc, Khi, Klo, Qhi, Qlo, Vtg);
    flash2<<<dim3(512), 128, 0, stream>>>(Khi, Klo, Qhi, Qlo, Vtg, Ou, zrow);
    reduce_kernel<<<dim3(BB * NHEADS), 256, 0, stream>>>(zrow, coef);
    conv1x1_kernel<<<cgrid, 256, 0, stream>>>(Ou, W4, b4, out, coef);
}

// Round 4
// 315.368 us; speedup vs baseline: 4.3498x; 1.5784x over previous
//
#include <hip/hip_runtime.h>
#include <math.h>

#define CC 256
#define NSP 4096
#define L2E 1.44269504088896340736f
#define SH2 (48.0f * L2E)

typedef float f32x4  __attribute__((ext_vector_type(4)));
typedef float f32x16 __attribute__((ext_vector_type(16)));
typedef _Float16 half8 __attribute__((ext_vector_type(8)));
typedef unsigned short u16;
typedef unsigned int   u32;

__device__ __forceinline__ void glds16(const void* gsrc, void* ldst) {
    __builtin_amdgcn_global_load_lds(
        (const __attribute__((address_space(1))) void*)gsrc,
        (__attribute__((address_space(3))) void*)ldst, 16, 0, 0);
}
__device__ __forceinline__ half8 ld_frag(const u16* p) {
    int4 v = *(const int4*)p;
    return __builtin_bit_cast(half8, v);
}
__device__ __forceinline__ u32 pkrtz(float a, float b) {
    return __builtin_bit_cast(u32, __builtin_amdgcn_cvt_pkrtz(a, b));
}
__device__ __forceinline__ u16 f16b(float x) {
    _Float16 h = (_Float16)x;
    return __builtin_bit_cast(u16, h);
}

// ---------------------------------------------------------------------------
// conv_pack<MODE>: out[b,o,s] = bias[o] + sum_c W[o,c] x[b,c,s], then:
//  MODE 0 (K): *L2E, f16 hi/lo split, frag-major chunks (m*64+ri within slab)
//  MODE 1 (Q): f16 single, same chunk layout
//  MODE 2 (V): f16 single, TRANSPOSED chunks (stile*64+f), via LDS repack
//  MODE 3 (O): x = 4 Opart partials summed * coef[bh], f32 out, no pack
// block 128 thr: thread = 4 consecutive s x 8 o.  grid (32 ot, 8 st, 2 b).
// chunk := 16B = 8 f16 = one MFMA lane-fragment slice (frag-major layout).
// ---------------------------------------------------------------------------
template<int MODE>
__global__ __launch_bounds__(128) void conv_pack(
    const float* __restrict__ x, const float* __restrict__ W,
    const float* __restrict__ bias,
    u16* __restrict__ outA, u16* __restrict__ outB,
    float* __restrict__ outF, const float* __restrict__ coef)
{
    __shared__ __align__(16) float xb[2][16 * 512];   // 64 KB dbuf
    const int tid = threadIdx.x;
    const int o0 = blockIdx.x * 8;
    const int s0 = blockIdx.y * 512;
    const int b  = blockIdx.z;

    f32x4 acc[8];
#pragma unroll
    for (int oo = 0; oo < 8; ++oo) {
        const float bv = bias[o0 + oo];
        acc[oo] = (f32x4){bv, bv, bv, bv};
    }

    int buf = 0;
    if constexpr (MODE != 3) {
        const float* src = x + (size_t)b * CC * NSP + s0;
#pragma unroll
        for (int i = 0; i < 16; ++i) {
            const int idx = tid + 128 * i;
            glds16(src + (idx >> 7) * NSP + (idx & 127) * 4,
                   (char*)&xb[0][0] + idx * 16);
        }
        asm volatile("s_waitcnt vmcnt(0)" ::: "memory");
        __syncthreads();
    }

    for (int ct = 0; ct < 16; ++ct) {
        if constexpr (MODE != 3) {
            if (ct < 15) {   // prefetch next chunk (m97 pattern: issue->compute->drain)
                const float* src = x + ((size_t)b * CC + (ct + 1) * 16) * NSP + s0;
#pragma unroll
                for (int i = 0; i < 16; ++i) {
                    const int idx = tid + 128 * i;
                    glds16(src + (idx >> 7) * NSP + (idx & 127) * 4,
                           (char*)&xb[buf ^ 1][0] + idx * 16);
                }
            }
        } else {
            __syncthreads();
#pragma unroll
            for (int i = 0; i < 16; ++i) {
                const int idx = tid + 128 * i;
                const int c = idx >> 7, sq = idx & 127;
                const int cg = ct * 16 + c;
                const size_t base = ((size_t)b * CC + cg) * NSP + s0 + sq * 4;
                f32x4 v = *(const f32x4*)(x + base)
                        + *(const f32x4*)(x + base + 2097152)
                        + *(const f32x4*)(x + base + 2 * 2097152)
                        + *(const f32x4*)(x + base + 3 * 2097152);
                v *= coef[b * 4 + (cg >> 6)];
                *(f32x4*)&xb[0][idx * 4] = v;
            }
            __syncthreads();
        }

        // compute: W addresses are wave-uniform -> s_load (SGPR fma operand)
#pragma unroll
        for (int cq = 0; cq < 4; ++cq) {
            f32x4 wv[8];
#pragma unroll
            for (int oo = 0; oo < 8; ++oo)
                wv[oo] = *(const f32x4*)&W[(o0 + oo) * CC + ct * 16 + cq * 4];
#pragma unroll
            for (int cc = 0; cc < 4; ++cc) {
                const f32x4 xv = *(const f32x4*)&xb[buf][(cq * 4 + cc) * 512 + tid * 4];
#pragma unroll
                for (int oo = 0; oo < 8; ++oo)
                    acc[oo] += wv[oo][cc] * xv;
            }
        }

        if constexpr (MODE != 3) {
            asm volatile("s_waitcnt vmcnt(0)" ::: "memory");
            __syncthreads();
            buf ^= 1;
        }
    }

    if constexpr (MODE == 3) {
#pragma unroll
        for (int oo = 0; oo < 8; ++oo)
            *(f32x4*)&outF[((size_t)b * CC + o0 + oo) * NSP + s0 + tid * 4] = acc[oo];
        return;
    }
    if constexpr (MODE == 0 || MODE == 1) {
        // chunk = 8 consecutive s = this thread (4 s) + lane partner (4 s)
        const int sg = s0 + tid * 4;
        const int ri = sg >> 6, m = (sg >> 3) & 7;
        const float sc = (MODE == 0) ? L2E : 1.0f;
#pragma unroll
        for (int oo = 0; oo < 8; ++oo) {
            const int c = o0 + oo;
            const int bhh = b * 4 + (c >> 6), t = c & 63;
            f32x4 av = acc[oo] * sc;
            u16 hb[4]; float lo[4];
#pragma unroll
            for (int j = 0; j < 4; ++j) {
                _Float16 hf = (_Float16)av[j];           // RNE
                hb[j] = __builtin_bit_cast(u16, hf);
                lo[j] = av[j] - (float)hf;
            }
            u32 wh0 = hb[0] | ((u32)hb[1] << 16);
            u32 wh1 = hb[2] | ((u32)hb[3] << 16);
            u32 ph0 = (u32)__shfl_xor((int)wh0, 1);
            u32 ph1 = (u32)__shfl_xor((int)wh1, 1);
            u32 wl0 = 0, wl1 = 0, pl0 = 0, pl1 = 0;
            if constexpr (MODE == 0) {
                wl0 = f16b(lo[0]) | ((u32)f16b(lo[1]) << 16);
                wl1 = f16b(lo[2]) | ((u32)f16b(lo[3]) << 16);
                pl0 = (u32)__shfl_xor((int)wl0, 1);
                pl1 = (u32)__shfl_xor((int)wl1, 1);
            }
            if (!(tid & 1)) {
                const size_t cix = ((size_t)(bhh * 64 + t) * 512 + m * 64 + ri) * 8;
                *(int4*)(outA + cix) = make_int4((int)wh0, (int)wh1, (int)ph0, (int)ph1);
                if constexpr (MODE == 0)
                    *(int4*)(outB + cix) = make_int4((int)wl0, (int)wl1, (int)pl0, (int)pl1);
            }
        }
        return;
    }
    // MODE 2 (V): transpose via LDS (chunk content is stride-64 in s)
    __syncthreads();
    float* sb = &xb[0][0];
#pragma unroll
    for (int oo = 0; oo < 8; ++oo)
        *(f32x4*)&sb[oo * 512 + tid * 4] = acc[oo];
    __syncthreads();
    const int wv2 = tid >> 6, lf = tid & 63;
#pragma unroll
    for (int i = 0; i < 4; ++i) {
        const int oo = wv2 * 4 + i;
        u16 hq[8];
#pragma unroll
        for (int q = 0; q < 8; ++q)
            hq[q] = f16b(sb[oo * 512 + q * 64 + lf]);
        const int c = o0 + oo;
        const int bhh = b * 4 + (c >> 6), tq = c & 63;
        const size_t cix = ((size_t)(bhh * 64 + tq) * 512 + blockIdx.y * 64 + lf) * 8;
        *(int4*)(outA + cix) = make_int4(
            (int)(hq[0] | ((u32)hq[1] << 16)), (int)(hq[2] | ((u32)hq[3] << 16)),
            (int)(hq[4] | ((u32)hq[5] << 16)), (int)(hq[6] | ((u32)hq[7] << 16)));
    }
}

// ---------------------------------------------------------------------------
// flash3: no LDS, no barriers. S^T = Q*K^T (32x32x16 f16, K hi/lo in regs,
// C-init = -48*log2e), P = exp2(S'), in-register P->A-frag via cvt_pkrtz +
// shfl_xor(32) + half-select, O += P*V. 4 waves x 64 K-rows; tq quartered.
// grid 512: bh = id&7 (XCD-pinned), tb = (id>>3)>>2, qq = (id>>3)&3.
// ---------------------------------------------------------------------------
__global__ __launch_bounds__(256, 2) void flash3(
    const u16* __restrict__ Khi, const u16* __restrict__ Klo,
    const u16* __restrict__ Qpk, const u16* __restrict__ Vpk,
    float* __restrict__ Opart, float* __restrict__ zpart)
{
    const int tid = threadIdx.x;
    const int w = tid >> 6, l = tid & 63;
    const int h = l >> 5, ln = l & 31;
    const int id = blockIdx.x;
    const int bh = id & 7, rest = id >> 3;
    const int tb = rest >> 2, qq = rest & 3;
    const int b = bh >> 2, hd = bh & 3;
    const int t = tb * 4 + w;

    const u16* Kh = Khi + (size_t)(bh * 64 + t) * 4096;
    const u16* Kl = Klo + (size_t)(bh * 64 + t) * 4096;

    half8 kf_h[2][4], kf_l[2][4];
#pragma unroll
    for (int rt = 0; rt < 2; ++rt)
#pragma unroll
        for (int ks = 0; ks < 4; ++ks) {
            const int cix = ((ks * 2 + h) * 64 + rt * 32 + ln) * 8;
            kf_h[rt][ks] = ld_frag(Kh + cix);
            kf_l[rt][ks] = ld_frag(Kl + cix);
        }

    f32x16 oacc[2][2];
#pragma unroll
    for (int rt = 0; rt < 2; ++rt)
#pragma unroll
        for (int ft = 0; ft < 2; ++ft)
#pragma unroll
            for (int i = 0; i < 16; ++i) oacc[rt][ft][i] = 0.f;
    float zacc[2] = {0.f, 0.f};

    for (int it = 0; it < 16; ++it) {
        const int tq = qq * 16 + it;
        const u16* Qt = Qpk + (size_t)(bh * 64 + tq) * 4096;
        const u16* Vt = Vpk + (size_t)(bh * 64 + tq) * 4096;
#pragma unroll
        for (int jt = 0; jt < 2; ++jt) {
            half8 qf[4];
#pragma unroll
            for (int ks = 0; ks < 4; ++ks)
                qf[ks] = ld_frag(Qt + ((ks * 2 + h) * 64 + jt * 32 + ln) * 8);

            f32x16 sa[2];
#pragma unroll
            for (int rt = 0; rt < 2; ++rt)
#pragma unroll
                for (int i = 0; i < 16; ++i) sa[rt][i] = -SH2;
#pragma unroll
            for (int ks = 0; ks < 4; ++ks) {
                sa[0] = __builtin_amdgcn_mfma_f32_32x32x16_f16(qf[ks], kf_h[0][ks], sa[0], 0, 0, 0);
                sa[1] = __builtin_amdgcn_mfma_f32_32x32x16_f16(qf[ks], kf_h[1][ks], sa[1], 0, 0, 0);
                sa[0] = __builtin_amdgcn_mfma_f32_32x32x16_f16(qf[ks], kf_l[0][ks], sa[0], 0, 0, 0);
                sa[1] = __builtin_amdgcn_mfma_f32_32x32x16_f16(qf[ks], kf_l[1][ks], sa[1], 0, 0, 0);
            }

            half8 vf[2][2];
#pragma unroll
            for (int js = 0; js < 2; ++js)
#pragma unroll
                for (int ft = 0; ft < 2; ++ft)
                    vf[js][ft] = ld_frag(Vt + (((jt * 2 + js) * 2 + h) * 64 + ft * 32 + ln) * 8);

#pragma unroll
            for (int rt = 0; rt < 2; ++rt) {
                float p[16]; float zs = 0.f;
#pragma unroll
                for (int i = 0; i < 16; ++i) { p[i] = exp2f(sa[rt][i]); zs += p[i]; }
                zacc[rt] += zs;
                u32 wd[8], sw[8];
#pragma unroll
                for (int i = 0; i < 8; ++i) wd[i] = pkrtz(p[2 * i], p[2 * i + 1]);
#pragma unroll
                for (int i = 0; i < 8; ++i) sw[i] = (u32)__shfl_xor((int)wd[i], 32);
                // lane h=0: [wd0,wd1,sw0,sw1] = P[r][j 0..7]; lane h=1: [sw2,sw3,wd2,wd3] = j 8..15
                int4 c0 = make_int4((int)(h ? sw[2] : wd[0]), (int)(h ? sw[3] : wd[1]),
                                    (int)(h ? wd[2] : sw[0]), (int)(h ? wd[3] : sw[1]));
                int4 c1 = make_int4((int)(h ? sw[6] : wd[4]), (int)(h ? sw[7] : wd[5]),
                                    (int)(h ? wd[6] : sw[4]), (int)(h ? wd[7] : sw[5]));
                const half8 pf0 = __builtin_bit_cast(half8, c0);
                const half8 pf1 = __builtin_bit_cast(half8, c1);
                oacc[rt][0] = __builtin_amdgcn_mfma_f32_32x32x16_f16(pf0, vf[0][0], oacc[rt][0], 0, 0, 0);
                oacc[rt][0] = __builtin_amdgcn_mfma_f32_32x32x16_f16(pf1, vf[1][0], oacc[rt][0], 0, 0, 0);
                oacc[rt][1] = __builtin_amdgcn_mfma_f32_32x32x16_f16(pf0, vf[0][1], oacc[rt][1], 0, 0, 0);
                oacc[rt][1] = __builtin_amdgcn_mfma_f32_32x32x16_f16(pf1, vf[1][1], oacc[rt][1], 0, 0, 0);
            }
        }
    }

#pragma unroll
    for (int rt = 0; rt < 2; ++rt) {
        const float z2 = zacc[rt] + __shfl_xor(zacc[rt], 32);
        if (h == 0)
            zpart[((size_t)qq * 8 + bh) * NSP + t * 64 + rt * 32 + ln] = z2;
    }
    const size_t ob = ((size_t)(qq * 2 + b) * CC + hd * 64 + t) * NSP;
#pragma unroll
    for (int rt = 0; rt < 2; ++rt)
#pragma unroll
        for (int ft = 0; ft < 2; ++ft)
#pragma unroll
            for (int reg = 0; reg < 16; ++reg) {
                const int rin = (reg & 3) + 8 * (reg >> 2) + 4 * h;
                Opart[ob + (size_t)(rt * 32 + rin) * 64 + ft * 32 + ln] = oacc[rt][ft][reg];
            }
}

// ---------------------------------------------------------------------------
__global__ __launch_bounds__(256) void reduce_kernel(
    const float* __restrict__ zp, float* __restrict__ coef)
{
    __shared__ float red[256];
    const int tid = threadIdx.x, bh = blockIdx.x;
    float lz = 0.f;
    for (int i = tid; i < 4 * NSP; i += 256) {
        const int qq = i >> 12, r = i & 4095;
        lz += zp[((size_t)qq * 8 + bh) * NSP + r];
    }
    red[tid] = lz; __syncthreads();
    for (int s = 128; s > 0; s >>= 1) {
        if (tid < s) red[tid] += red[tid + s];
        __syncthreads();
    }
    if (tid == 0) coef[bh] = 1.f / red[0];
}

// ---------------------------------------------------------------------------
extern "C" void kernel_launch(void* const* d_in, const int* in_sizes, int n_in,
                              void* d_out, int out_size, void* d_ws, size_t ws_size,
                              hipStream_t stream)
{
    (void)in_sizes; (void)n_in; (void)out_size; (void)ws_size;
    const float* in1 = (const float*)d_in[0];
    const float* in2 = (const float*)d_in[1];
    const float* W1 = (const float*)d_in[2]; const float* b1 = (const float*)d_in[3];
    const float* W2 = (const float*)d_in[4]; const float* b2 = (const float*)d_in[5];
    const float* W3 = (const float*)d_in[6]; const float* b3 = (const float*)d_in[7];
    const float* W4 = (const float*)d_in[8]; const float* b4 = (const float*)d_in[9];
    float* out = (float*)d_out;

    const size_t TEN = (size_t)2 * CC * NSP;          // 2,097,152 elements
    char* p = (char*)d_ws;
    u16* Khi = (u16*)p; p += TEN * 2;                 // 4 MB each
    u16* Klo = (u16*)p; p += TEN * 2;
    u16* Qpk = (u16*)p; p += TEN * 2;
    u16* Vpk = (u16*)p; p += TEN * 2;
    float* Opart = (float*)p; p += 4 * TEN * 4;       // 32 MB (4 tq-quarter partials)
    float* zpart = (float*)p; p += (size_t)4 * 8 * NSP * 4;
    float* coef  = (float*)p;

    dim3 cgrid(32, 8, 2), cblk(128);
    conv_pack<0><<<cgrid, cblk, 0, stream>>>(in1, W1, b1, Khi, Klo, nullptr, nullptr);
    conv_pack<1><<<cgrid, cblk, 0, stream>>>(in1, W2, b2, Qpk, nullptr, nullptr, nullptr);
    conv_pack<2><<<cgrid, cblk, 0, stream>>>(in2, W3, b3, Vpk, nullptr, nullptr, nullptr);
    flash3<<<dim3(512), 256, 0, stream>>>(Khi, Klo, Qpk, Vpk, Opart, zpart);
    reduce_kernel<<<dim3(8), 256, 0, stream>>>(zpart, coef);
    conv_pack<3><<<cgrid, cblk, 0, stream>>>(Opart, W4, b4, nullptr, nullptr, out, coef);
}

// Round 5
// 226.509 us; speedup vs baseline: 6.0562x; 1.3923x over previous
//
#include <hip/hip_runtime.h>
#include <math.h>

#define CC 256
#define NSP 4096
#define L2E 1.44269504088896340736f
#define SH2 (48.0f * L2E)

typedef float f32x2  __attribute__((ext_vector_type(2)));
typedef float f32x4  __attribute__((ext_vector_type(4)));
typedef float f32x16 __attribute__((ext_vector_type(16)));
typedef _Float16 half8 __attribute__((ext_vector_type(8)));
typedef unsigned short u16;
typedef unsigned int   u32;

__device__ __forceinline__ half8 ld_frag(const u16* p) {
    int4 v = *(const int4*)p;
    return __builtin_bit_cast(half8, v);
}
__device__ __forceinline__ u32 pkrtz(float a, float b) {
    return __builtin_bit_cast(u32, __builtin_amdgcn_cvt_pkrtz(a, b));
}
__device__ __forceinline__ u16 f16b(float x) {
    _Float16 h = (_Float16)x;
    return __builtin_bit_cast(u16, h);
}

// ---------------------------------------------------------------------------
// conv_qkv: all three projections in ONE launch (768 blocks = 3072 waves =
// 3 waves/SIMD). No LDS on K/Q path, x read straight from global (coalesced),
// W wave-uniform (scalar cache). Epilogues emit the SAME packed layouts R4
// verified: K hi/lo f16 (xL2E), Q f16, V transposed f16, all frag-major.
//   id <  256: K  (o-tile 32, s-tile 256, 1 s/thread)
//   id <  512: Q  (same)
//   id >= 512: V  (o-tile 16, s-tile 512, 2 s/thread, 16 KB LDS transpose)
// ---------------------------------------------------------------------------
__global__ __launch_bounds__(256) void conv_qkv(
    const float* __restrict__ in1, const float* __restrict__ in2,
    const float* __restrict__ W1, const float* __restrict__ b1,
    const float* __restrict__ W2, const float* __restrict__ b2,
    const float* __restrict__ W3, const float* __restrict__ b3,
    u16* __restrict__ Khi, u16* __restrict__ Klo,
    u16* __restrict__ Qpk, u16* __restrict__ Vpk)
{
    __shared__ __align__(16) u16 sb16[16 * 512];   // V-path transpose buffer
    const int tid = threadIdx.x;
    const int id  = blockIdx.x;

    if (id < 512) {
        // -------------------- K / Q --------------------
        const int kind = id >> 8;              // 0 = K, 1 = Q
        const int kid  = id & 255;
        const int ot   = kid >> 5;             // 0..7
        const int stb  = kid & 31;
        const int b    = stb >> 4;
        const int s0   = (stb & 15) * 256;
        const int o0   = ot * 32;
        const float* W    = kind ? W2 : W1;
        const float* bias = kind ? b2 : b1;

        const int sg = s0 + tid;
        const float* xp = in1 + (size_t)b * CC * NSP + sg;

        float acc[32];
#pragma unroll
        for (int oo = 0; oo < 32; ++oo) acc[oo] = bias[o0 + oo];

        for (int c4 = 0; c4 < 64; ++c4) {
            float xv[4];
#pragma unroll
            for (int cc = 0; cc < 4; ++cc)
                xv[cc] = xp[(size_t)(c4 * 4 + cc) * NSP];
#pragma unroll
            for (int og = 0; og < 4; ++og) {
                f32x4 wv[8];
#pragma unroll
                for (int j = 0; j < 8; ++j)
                    wv[j] = *(const f32x4*)&W[(o0 + og * 8 + j) * CC + c4 * 4];
#pragma unroll
                for (int j = 0; j < 8; ++j)
#pragma unroll
                    for (int cc = 0; cc < 4; ++cc)
                        acc[og * 8 + j] += wv[j][cc] * xv[cc];
            }
        }

        const float sc = kind ? 1.0f : L2E;
        const int m  = (sg >> 3) & 7;
        const int ri = sg >> 6;
        u16* outA = kind ? Qpk : Khi;
#pragma unroll
        for (int oo = 0; oo < 32; ++oo) {
            const int c    = o0 + oo;
            const int slab = (b * 4 + (c >> 6)) * 64 + (c & 63);
            const float av = acc[oo] * sc;
            const _Float16 hf = (_Float16)av;          // RNE
            u32 h  = (u32)__builtin_bit_cast(u16, hf);
            u32 p0 = h | ((u32)__shfl_xor((int)h, 1) << 16);
            u32 p2 = (u32)__shfl_xor((int)p0, 2);
            u32 p4 = (u32)__shfl_xor((int)p0, 4);
            u32 p6 = (u32)__shfl_xor((int)p0, 6);
            if (!(tid & 7))
                *(int4*)(outA + ((size_t)slab * 512 + m * 64 + ri) * 8)
                    = make_int4((int)p0, (int)p2, (int)p4, (int)p6);
            if (kind == 0) {
                const float lo = av - (float)hf;
                u32 hl = (u32)f16b(lo);
                u32 q0 = hl | ((u32)__shfl_xor((int)hl, 1) << 16);
                u32 q2 = (u32)__shfl_xor((int)q0, 2);
                u32 q4 = (u32)__shfl_xor((int)q0, 4);
                u32 q6 = (u32)__shfl_xor((int)q0, 6);
                if (!(tid & 7))
                    *(int4*)(Klo + ((size_t)slab * 512 + m * 64 + ri) * 8)
                        = make_int4((int)q0, (int)q2, (int)q4, (int)q6);
            }
        }
    } else {
        // -------------------- V (transposed pack) --------------------
        const int vid = id - 512;
        const int ot  = vid >> 4;              // 0..15
        const int stb = vid & 15;
        const int b   = stb >> 3;
        const int st8 = stb & 7;
        const int s0  = st8 * 512;
        const int o0  = ot * 16;

        const int sg = s0 + tid * 2;
        const float* xp = in2 + (size_t)b * CC * NSP + sg;

        f32x2 acc[16];
#pragma unroll
        for (int oo = 0; oo < 16; ++oo) {
            const float bv = b3[o0 + oo];
            acc[oo] = (f32x2){bv, bv};
        }
        for (int c4 = 0; c4 < 64; ++c4) {
            f32x2 xv[4];
#pragma unroll
            for (int cc = 0; cc < 4; ++cc)
                xv[cc] = *(const f32x2*)&xp[(size_t)(c4 * 4 + cc) * NSP];
#pragma unroll
            for (int og = 0; og < 2; ++og) {
                f32x4 wv[8];
#pragma unroll
                for (int j = 0; j < 8; ++j)
                    wv[j] = *(const f32x4*)&W3[(o0 + og * 8 + j) * CC + c4 * 4];
#pragma unroll
                for (int j = 0; j < 8; ++j)
#pragma unroll
                    for (int cc = 0; cc < 4; ++cc)
                        acc[og * 8 + j] += wv[j][cc] * xv[cc];
            }
        }
#pragma unroll
        for (int oo = 0; oo < 16; ++oo)
            *(u32*)&sb16[oo * 512 + tid * 2]
                = (u32)f16b(acc[oo][0]) | ((u32)f16b(acc[oo][1]) << 16);
        __syncthreads();
#pragma unroll
        for (int i = 0; i < 4; ++i) {
            const int task = tid + 256 * i;
            const int oo = task >> 6, f = task & 63;
            u16 hq[8];
#pragma unroll
            for (int q = 0; q < 8; ++q) hq[q] = sb16[oo * 512 + q * 64 + f];
            const int c    = o0 + oo;
            const int slab = (b * 4 + (c >> 6)) * 64 + (c & 63);
            *(int4*)(Vpk + ((size_t)slab * 512 + st8 * 64 + f) * 8) = make_int4(
                (int)((u32)hq[0] | ((u32)hq[1] << 16)), (int)((u32)hq[2] | ((u32)hq[3] << 16)),
                (int)((u32)hq[4] | ((u32)hq[5] << 16)), (int)((u32)hq[6] | ((u32)hq[7] << 16)));
        }
    }
}

// ---------------------------------------------------------------------------
// flash3 (verbatim from R4): no LDS, no barriers. S^T = Q*K^T (32x32x16 f16,
// K hi/lo in regs, C-init = -48*log2e), P = exp2(S'), in-register P->A-frag
// via cvt_pkrtz + shfl_xor(32) + half-select, O += P*V.
// grid 512: bh = id&7 (XCD-pinned), tb = (id>>3)>>2, qq = (id>>3)&3.
// ---------------------------------------------------------------------------
__global__ __launch_bounds__(256, 2) void flash3(
    const u16* __restrict__ Khi, const u16* __restrict__ Klo,
    const u16* __restrict__ Qpk, const u16* __restrict__ Vpk,
    float* __restrict__ Opart, float* __restrict__ zpart)
{
    const int tid = threadIdx.x;
    const int w = tid >> 6, l = tid & 63;
    const int h = l >> 5, ln = l & 31;
    const int id = blockIdx.x;
    const int bh = id & 7, rest = id >> 3;
    const int tb = rest >> 2, qq = rest & 3;
    const int b = bh >> 2, hd = bh & 3;
    const int t = tb * 4 + w;

    const u16* Kh = Khi + (size_t)(bh * 64 + t) * 4096;
    const u16* Kl = Klo + (size_t)(bh * 64 + t) * 4096;

    half8 kf_h[2][4], kf_l[2][4];
#pragma unroll
    for (int rt = 0; rt < 2; ++rt)
#pragma unroll
        for (int ks = 0; ks < 4; ++ks) {
            const int cix = ((ks * 2 + h) * 64 + rt * 32 + ln) * 8;
            kf_h[rt][ks] = ld_frag(Kh + cix);
            kf_l[rt][ks] = ld_frag(Kl + cix);
        }

    f32x16 oacc[2][2];
#pragma unroll
    for (int rt = 0; rt < 2; ++rt)
#pragma unroll
        for (int ft = 0; ft < 2; ++ft)
#pragma unroll
            for (int i = 0; i < 16; ++i) oacc[rt][ft][i] = 0.f;
    float zacc[2] = {0.f, 0.f};

    for (int it = 0; it < 16; ++it) {
        const int tq = qq * 16 + it;
        const u16* Qt = Qpk + (size_t)(bh * 64 + tq) * 4096;
        const u16* Vt = Vpk + (size_t)(bh * 64 + tq) * 4096;
#pragma unroll
        for (int jt = 0; jt < 2; ++jt) {
            half8 qf[4];
#pragma unroll
            for (int ks = 0; ks < 4; ++ks)
                qf[ks] = ld_frag(Qt + ((ks * 2 + h) * 64 + jt * 32 + ln) * 8);

            f32x16 sa[2];
#pragma unroll
            for (int rt = 0; rt < 2; ++rt)
#pragma unroll
                for (int i = 0; i < 16; ++i) sa[rt][i] = -SH2;
#pragma unroll
            for (int ks = 0; ks < 4; ++ks) {
                sa[0] = __builtin_amdgcn_mfma_f32_32x32x16_f16(qf[ks], kf_h[0][ks], sa[0], 0, 0, 0);
                sa[1] = __builtin_amdgcn_mfma_f32_32x32x16_f16(qf[ks], kf_h[1][ks], sa[1], 0, 0, 0);
                sa[0] = __builtin_amdgcn_mfma_f32_32x32x16_f16(qf[ks], kf_l[0][ks], sa[0], 0, 0, 0);
                sa[1] = __builtin_amdgcn_mfma_f32_32x32x16_f16(qf[ks], kf_l[1][ks], sa[1], 0, 0, 0);
            }

            half8 vf[2][2];
#pragma unroll
            for (int js = 0; js < 2; ++js)
#pragma unroll
                for (int ft = 0; ft < 2; ++ft)
                    vf[js][ft] = ld_frag(Vt + (((jt * 2 + js) * 2 + h) * 64 + ft * 32 + ln) * 8);

#pragma unroll
            for (int rt = 0; rt < 2; ++rt) {
                float p[16]; float zs = 0.f;
#pragma unroll
                for (int i = 0; i < 16; ++i) { p[i] = exp2f(sa[rt][i]); zs += p[i]; }
                zacc[rt] += zs;
                u32 wd[8], sw[8];
#pragma unroll
                for (int i = 0; i < 8; ++i) wd[i] = pkrtz(p[2 * i], p[2 * i + 1]);
#pragma unroll
                for (int i = 0; i < 8; ++i) sw[i] = (u32)__shfl_xor((int)wd[i], 32);
                int4 c0 = make_int4((int)(h ? sw[2] : wd[0]), (int)(h ? sw[3] : wd[1]),
                                    (int)(h ? wd[2] : sw[0]), (int)(h ? wd[3] : sw[1]));
                int4 c1 = make_int4((int)(h ? sw[6] : wd[4]), (int)(h ? sw[7] : wd[5]),
                                    (int)(h ? wd[6] : sw[4]), (int)(h ? wd[7] : sw[5]));
                const half8 pf0 = __builtin_bit_cast(half8, c0);
                const half8 pf1 = __builtin_bit_cast(half8, c1);
                oacc[rt][0] = __builtin_amdgcn_mfma_f32_32x32x16_f16(pf0, vf[0][0], oacc[rt][0], 0, 0, 0);
                oacc[rt][0] = __builtin_amdgcn_mfma_f32_32x32x16_f16(pf1, vf[1][0], oacc[rt][0], 0, 0, 0);
                oacc[rt][1] = __builtin_amdgcn_mfma_f32_32x32x16_f16(pf0, vf[0][1], oacc[rt][1], 0, 0, 0);
                oacc[rt][1] = __builtin_amdgcn_mfma_f32_32x32x16_f16(pf1, vf[1][1], oacc[rt][1], 0, 0, 0);
            }
        }
    }

#pragma unroll
    for (int rt = 0; rt < 2; ++rt) {
        const float z2 = zacc[rt] + __shfl_xor(zacc[rt], 32);
        if (h == 0)
            zpart[((size_t)qq * 8 + bh) * NSP + t * 64 + rt * 32 + ln] = z2;
    }
    const size_t ob = ((size_t)(qq * 2 + b) * CC + hd * 64 + t) * NSP;
#pragma unroll
    for (int rt = 0; rt < 2; ++rt)
#pragma unroll
        for (int ft = 0; ft < 2; ++ft)
#pragma unroll
            for (int reg = 0; reg < 16; ++reg) {
                const int rin = (reg & 3) + 8 * (reg >> 2) + 4 * h;
                Opart[ob + (size_t)(rt * 32 + rin) * 64 + ft * 32 + ln] = oacc[rt][ft][reg];
            }
}

// ---------------------------------------------------------------------------
__global__ __launch_bounds__(256) void reduce_kernel(
    const float* __restrict__ zp, float* __restrict__ coef)
{
    __shared__ float red[256];
    const int tid = threadIdx.x, bh = blockIdx.x;
    float lz = 0.f;
    for (int i = tid; i < 4 * NSP; i += 256) {
        const int qq = i >> 12, r = i & 4095;
        lz += zp[((size_t)qq * 8 + bh) * NSP + r];
    }
    red[tid] = lz; __syncthreads();
    for (int s = 128; s > 0; s >>= 1) {
        if (tid < s) red[tid] += red[tid + s];
        __syncthreads();
    }
    if (tid == 0) coef[bh] = 1.f / red[0];
}

// ---------------------------------------------------------------------------
// presum: Osum = (sum of 4 tq-quarter partials) * coef[bh].  Pure BW.
// grid 2048 x 256, one f32x4 per thread.
// ---------------------------------------------------------------------------
__global__ __launch_bounds__(256) void presum(
    const float* __restrict__ Opart, const float* __restrict__ coef,
    float* __restrict__ Osum)
{
    const size_t TEN = (size_t)2 * CC * NSP;
    const size_t i = ((size_t)blockIdx.x * 256 + threadIdx.x) * 4;
    f32x4 v = *(const f32x4*)(Opart + i)
            + *(const f32x4*)(Opart + TEN + i)
            + *(const f32x4*)(Opart + 2 * TEN + i)
            + *(const f32x4*)(Opart + 3 * TEN + i);
    const int c = (int)((i >> 12) & 255), b = (int)(i >> 20);
    v *= coef[b * 4 + (c >> 6)];
    *(f32x4*)(Osum + i) = v;
}

// ---------------------------------------------------------------------------
// conv_out: out = W4 . Osum + b4, f32.  o-tile 16, s-tile 512, 2 s/thread.
// grid 256 blocks x 256 thr (1024 waves = 1/SIMD).
// ---------------------------------------------------------------------------
__global__ __launch_bounds__(256) void conv_out(
    const float* __restrict__ Osum, const float* __restrict__ W4,
    const float* __restrict__ b4, float* __restrict__ out)
{
    const int tid = threadIdx.x;
    const int id  = blockIdx.x;
    const int ot  = id >> 4, stb = id & 15;
    const int b   = stb >> 3, s0 = (stb & 7) * 512;
    const int o0  = ot * 16;

    const int sg = s0 + tid * 2;
    const float* xp = Osum + (size_t)b * CC * NSP + sg;

    f32x2 acc[16];
#pragma unroll
    for (int oo = 0; oo < 16; ++oo) {
        const float bv = b4[o0 + oo];
        acc[oo] = (f32x2){bv, bv};
    }
    for (int c4 = 0; c4 < 64; ++c4) {
        f32x2 xv[4];
#pragma unroll
        for (int cc = 0; cc < 4; ++cc)
            xv[cc] = *(const f32x2*)&xp[(size_t)(c4 * 4 + cc) * NSP];
#pragma unroll
        for (int og = 0; og < 2; ++og) {
            f32x4 wv[8];
#pragma unroll
            for (int j = 0; j < 8; ++j)
                wv[j] = *(const f32x4*)&W4[(o0 + og * 8 + j) * CC + c4 * 4];
#pragma unroll
            for (int j = 0; j < 8; ++j)
#pragma unroll
                for (int cc = 0; cc < 4; ++cc)
                    acc[og * 8 + j] += wv[j][cc] * xv[cc];
        }
    }
#pragma unroll
    for (int oo = 0; oo < 16; ++oo)
        *(f32x2*)&out[((size_t)b * CC + o0 + oo) * NSP + sg] = acc[oo];
}

// ---------------------------------------------------------------------------
extern "C" void kernel_launch(void* const* d_in, const int* in_sizes, int n_in,
                              void* d_out, int out_size, void* d_ws, size_t ws_size,
                              hipStream_t stream)
{
    (void)in_sizes; (void)n_in; (void)out_size; (void)ws_size;
    const float* in1 = (const float*)d_in[0];
    const float* in2 = (const float*)d_in[1];
    const float* W1 = (const float*)d_in[2]; const float* b1 = (const float*)d_in[3];
    const float* W2 = (const float*)d_in[4]; const float* b2 = (const float*)d_in[5];
    const float* W3 = (const float*)d_in[6]; const float* b3 = (const float*)d_in[7];
    const float* W4 = (const float*)d_in[8]; const float* b4 = (const float*)d_in[9];
    float* out = (float*)d_out;

    const size_t TEN = (size_t)2 * CC * NSP;          // 2,097,152 elements
    char* p = (char*)d_ws;
    u16* Khi = (u16*)p; p += TEN * 2;                 // 4 MB each
    u16* Klo = (u16*)p; p += TEN * 2;
    u16* Qpk = (u16*)p; p += TEN * 2;
    u16* Vpk = (u16*)p; p += TEN * 2;
    float* Opart = (float*)p; p += 4 * TEN * 4;       // 32 MB (4 tq-quarter partials)
    float* zpart = (float*)p; p += (size_t)4 * 8 * NSP * 4;
    float* coef  = (float*)p;
    float* Osum  = (float*)Khi;   // alias: Khi/Klo (8 MB) dead after flash3

    conv_qkv<<<dim3(768), 256, 0, stream>>>(in1, in2, W1, b1, W2, b2, W3, b3,
                                            Khi, Klo, Qpk, Vpk);
    flash3<<<dim3(512), 256, 0, stream>>>(Khi, Klo, Qpk, Vpk, Opart, zpart);
    reduce_kernel<<<dim3(8), 256, 0, stream>>>(zpart, coef);
    presum<<<dim3(2048), 256, 0, stream>>>(Opart, coef, Osum);
    conv_out<<<dim3(256), 256, 0, stream>>>(Osum, W4, b4, out);
}